// Round 4
// baseline (78.063 us; speedup 1.0000x reference)
//
#include <hip/hip_runtime.h>

// MaxUnpooling2D, up=(2,2).
// updates: [B=16, H=64, W=64, C=256] f32
// mask:    same shape, int32 flat index into out [B, 128, 128, 256]
// out:     [16, 128, 128, 256] f32
//
// Gather formulation: each thread handles pooled cells x 4 channels.
// Mask construction guarantees each mask entry lands in its own 2x2 window
// at its own channel, so out[o] = (mask==o) ? updates : 0 over the 4 window
// candidates covers every output element exactly once -> no pre-zero,
// fully coalesced reads AND writes. All accesses non-temporal (zero reuse).
//
// R3: 2048 blocks x 8 cells/thread (contiguous per block), unroll 4 ->
// more loads in flight per wave, 8x fewer block dispatches.

typedef float  f32x4 __attribute__((ext_vector_type(4)));
typedef int    i32x4 __attribute__((ext_vector_type(4)));

constexpr int B = 16, H = 64, W = 64, C = 256;
constexpr int W2 = 128;                     // 2*W
constexpr int TOTAL4 = B * H * W * C / 4;   // 4,194,304 thread-units
constexpr int BLK   = 256;
constexpr int GRID  = 2048;
constexpr int ITERS = TOTAL4 / (BLK * GRID);   // 8

__global__ __launch_bounds__(256) void
unpool_gather_kernel(const f32x4* __restrict__ upd,
                     const i32x4* __restrict__ msk,
                     f32x4* __restrict__ out)
{
    // Block owns a contiguous run of ITERS*BLK quad-cells.
    int base = blockIdx.x * (ITERS * BLK) + threadIdx.x;

    #pragma unroll 4
    for (int t = 0; t < ITERS; ++t) {
        int i = base + t * BLK;

        // i -> (spatial cell, channel-quad)
        int c  = (i & 63) << 2;        // channel base, C/4 = 64 quads
        int sp = i >> 6;               // hb*W + w, where hb = b*H + h
        int w  = sp & 63;              // W = 64
        int hb = sp >> 6;              // b*H + h

        // Output flat index of (b, 2h, 2w, c): b*H2+2h == 2*hb
        int o00 = 2 * (hb * W2 + w) * C + c;
        int o01 = o00 + C;             // (2h, 2w+1)
        int o10 = o00 + W2 * C;        // (2h+1, 2w)
        int o11 = o10 + C;             // (2h+1, 2w+1)

        i32x4 m = __builtin_nontemporal_load(msk + i);
        f32x4 u = __builtin_nontemporal_load(upd + i);

        f32x4 r00, r01, r10, r11;
        #pragma unroll
        for (int j = 0; j < 4; ++j) {
            r00[j] = (m[j] == o00 + j) ? u[j] : 0.0f;
            r01[j] = (m[j] == o01 + j) ? u[j] : 0.0f;
            r10[j] = (m[j] == o10 + j) ? u[j] : 0.0f;
            r11[j] = (m[j] == o11 + j) ? u[j] : 0.0f;
        }

        __builtin_nontemporal_store(r00, out + (o00 >> 2));
        __builtin_nontemporal_store(r01, out + (o01 >> 2));
        __builtin_nontemporal_store(r10, out + (o10 >> 2));
        __builtin_nontemporal_store(r11, out + (o11 >> 2));
    }
}

extern "C" void kernel_launch(void* const* d_in, const int* in_sizes, int n_in,
                              void* d_out, int out_size, void* d_ws, size_t ws_size,
                              hipStream_t stream)
{
    const f32x4* upd = (const f32x4*)d_in[0];
    const i32x4* msk = (const i32x4*)d_in[1];
    f32x4*       out = (f32x4*)d_out;

    unpool_gather_kernel<<<GRID, BLK, 0, stream>>>(upd, msk, out);
}

// Round 5
// 60.451 us; speedup vs baseline: 1.2913x; 1.2913x over previous
//
#include <hip/hip_runtime.h>

// MaxUnpooling2D, up=(2,2).
// updates: [B=16, H=64, W=64, C=256] f32
// mask:    same shape, int32 flat index into out [B, 128, 128, 256]
// out:     [16, 128, 128, 256] f32
//
// R4: output-indexed gather. One thread per output channel-quad:
//   out[o..o+3] = (mask[src]==o+j) ? updates[src] : 0
// where src is the unique pooled cell (b, y/2, x/2, c) that can produce
// output (b,y,x,c). Writes are one monotonic stream (fill-like, 1 store
// per thread, nontemporal). Reads coalesced 1 KiB/wave; 4x re-read is
// absorbed by L1 (x-pair, within block) and L2 (y-pair, 32 blocks later,
// same XCD under round-robin) -> HBM read traffic stays ~unique.

typedef float  f32x4 __attribute__((ext_vector_type(4)));
typedef int    i32x4 __attribute__((ext_vector_type(4)));

constexpr int B = 16, H = 64, W = 64, C = 256;
constexpr int OUT4 = B * (2*H) * (2*W) * C / 4;   // 16,777,216 output quads
constexpr int BLK  = 256;
constexpr int GRID = OUT4 / BLK;                  // 65536 blocks

__global__ __launch_bounds__(256) void
unpool_gather_out_kernel(const f32x4* __restrict__ upd,
                         const i32x4* __restrict__ msk,
                         f32x4* __restrict__ out)
{
    int tid = blockIdx.x * blockDim.x + threadIdx.x;   // output quad index

    // tid -> (b, y, x, cq) in [B, 128, 128, 64]
    int cq = tid & 63;
    int x  = (tid >> 6)  & 127;
    int y  = (tid >> 13) & 127;
    int b  =  tid >> 20;

    // unique producing input cell: (b, y>>1, x>>1, cq) in [16, 64, 64, 64]
    int iin = (b << 18) | ((y >> 1) << 12) | ((x >> 1) << 6) | cq;

    i32x4 m = msk[iin];
    f32x4 u = upd[iin];

    int o = tid << 2;   // output element base index
    f32x4 r;
    #pragma unroll
    for (int j = 0; j < 4; ++j)
        r[j] = (m[j] == o + j) ? u[j] : 0.0f;

    __builtin_nontemporal_store(r, out + tid);
}

extern "C" void kernel_launch(void* const* d_in, const int* in_sizes, int n_in,
                              void* d_out, int out_size, void* d_ws, size_t ws_size,
                              hipStream_t stream)
{
    const f32x4* upd = (const f32x4*)d_in[0];
    const i32x4* msk = (const i32x4*)d_in[1];
    f32x4*       out = (f32x4*)d_out;

    unpool_gather_out_kernel<<<GRID, BLK, 0, stream>>>(upd, msk, out);
}